// Round 2
// baseline (180.745 us; speedup 1.0000x reference)
//
#include <hip/hip_runtime.h>
#include <hip/hip_bf16.h>
#include <math.h>

// GQA attention forward, MI355X. Round 11: r10 base + attn LDS-instr reduction.
//  - attn: 256-thr blocks (4 waves = 2 teams x 2 waves), 32 q-rows per wave
//    (two stacked 16-row MFMA A-frags). K/V fragment reads amortized over 2x
//    work: wave-steps/block 132 -> 66, LDS b128-equiv/block 2904 -> 1716.
//  - prep/proj/oproj unchanged (RoPE table kept from r10).
// ws (u16): Xq 2M | Xk 2M | Xv 2M | Wt 1.5M | wot 1M | Qr 2M | Kr 512K | Vrt 512K | AO 2M | rope 512KB(f32)

#define SEQ 2048
#define DM 1024
#define HD 64

using u16 = unsigned short;
typedef __attribute__((ext_vector_type(8))) short bf16x8;
typedef __attribute__((ext_vector_type(4))) float f32x4;

// 1/sqrt(64) * log2(e): softmax in exp2 domain.
#define QSCALE 0.18033688011112042f

__device__ __forceinline__ u16 f2b(float f) {              // RNE
    union { float f; unsigned int i; } v; v.f = f;
    unsigned int u = v.i;
    return (u16)((u + 0x7fffu + ((u >> 16) & 1u)) >> 16);
}
__device__ __forceinline__ u16 f2b_fast(float f) {         // biased round
    union { float f; unsigned int i; } v; v.f = f;
    return (u16)((v.i + 0x8000u) >> 16);
}

// ---------------------------------------------------------------- prep
// [0,640): weight 64x64 transposes fp32->bf16 row-major [n][k].
// [640,1408): q/k/v fp32 -> bf16 row-major.
// [1408,1416): RoPE table rope[m][pi] = {cos(m*theta_pi), sin(m*theta_pi)}.
__global__ __launch_bounds__(256) void prep_kernel(
    const float* __restrict__ qin, const float* __restrict__ kin, const float* __restrict__ vin,
    const float* __restrict__ Wq, const float* __restrict__ Wk,
    const float* __restrict__ Wv, const float* __restrict__ Wo,
    u16* __restrict__ Xq, u16* __restrict__ Xk, u16* __restrict__ Xv,
    u16* __restrict__ Wt, u16* __restrict__ wot, float2* __restrict__ rope)
{
    const int b = blockIdx.x;
    const int t = threadIdx.x;

    if (b < 640) {
        __shared__ short T[64][72];
        const float* W; u16* dst; int N, t0, rowoff;
        if (b < 256)      { W = Wq; dst = Wt;  N = 1024; t0 = b;       rowoff = 0; }
        else if (b < 320) { W = Wk; dst = Wt;  N = 256;  t0 = b - 256; rowoff = 1024; }
        else if (b < 384) { W = Wv; dst = Wt;  N = 256;  t0 = b - 320; rowoff = 1280; }
        else              { W = Wo; dst = wot; N = 1024; t0 = b - 384; rowoff = 0; }
        const int ntn = N >> 6;
        const int k0 = (t0 / ntn) * 64, n0 = (t0 % ntn) * 64;
        const int r = t >> 4, c4 = (t & 15) * 4;
        #pragma unroll
        for (int rr = 0; rr < 4; ++rr) {
            const int k = r + rr * 16;
            float4 w4 = *reinterpret_cast<const float4*>(W + (size_t)(k0 + k) * N + n0 + c4);
            T[c4 + 0][k] = (short)f2b(w4.x);
            T[c4 + 1][k] = (short)f2b(w4.y);
            T[c4 + 2][k] = (short)f2b(w4.z);
            T[c4 + 3][k] = (short)f2b(w4.w);
        }
        __syncthreads();
        const int n = t >> 2, ck = (t & 3) * 16;
        u16* dp = dst + (size_t)(rowoff + n0 + n) * DM + k0 + ck;
        *reinterpret_cast<bf16x8*>(dp)     = *reinterpret_cast<const bf16x8*>(&T[n][ck]);
        *reinterpret_cast<bf16x8*>(dp + 8) = *reinterpret_cast<const bf16x8*>(&T[n][ck + 8]);
    } else if (b < 1408) {
        const int idx = b - 640;
        const int which = idx >> 8;
        const int ib = idx & 255;
        const float* src = (which == 0) ? qin : (which == 1) ? kin : vin;
        u16* dst = (which == 0) ? Xq : (which == 1) ? Xk : Xv;
        const size_t base = (size_t)ib * 8192 + (size_t)t * 32;
        #pragma unroll
        for (int c = 0; c < 4; ++c) {
            float4 x0 = *reinterpret_cast<const float4*>(src + base + c * 8);
            float4 x1 = *reinterpret_cast<const float4*>(src + base + c * 8 + 4);
            bf16x8 o;
            o[0] = (short)f2b(x0.x); o[1] = (short)f2b(x0.y);
            o[2] = (short)f2b(x0.z); o[3] = (short)f2b(x0.w);
            o[4] = (short)f2b(x1.x); o[5] = (short)f2b(x1.y);
            o[6] = (short)f2b(x1.z); o[7] = (short)f2b(x1.w);
            *reinterpret_cast<bf16x8*>(dst + base + c * 8) = o;
        }
    } else {
        // RoPE table: one thread per position m, 32 (cos,sin) pairs each.
        const int m = (b - 1408) * 256 + t;
        float2* rp = rope + (size_t)m * 32;
        for (int pi = 0; pi < 32; ++pi) {
            const float theta = exp2f(-0.8304820237f * (float)pi);  // 10000^(-pi/16)
            float sn, cs;
            sincosf((float)m * theta, &sn, &cs);
            rp[pi] = make_float2(cs, sn);
        }
    }
}

// ---------------------------------------------------------------- projections
// Unified QKV: grid (24, 32), 64x64 tile, BK=64, dbuf + reg prefetch,
// 1 barrier/iter. Cols [0,1024)=Q (RoPE*QSCALE), [1024,1280)=K (RoPE),
// [1280,1536)=V (transposed + key-permuted store).
__global__ __launch_bounds__(256) void proj_mfma(
    const u16* __restrict__ Xq, const u16* __restrict__ Xk, const u16* __restrict__ Xv,
    const u16* __restrict__ Wt,
    const float* __restrict__ bq, const float* __restrict__ bk, const float* __restrict__ bv,
    const float2* __restrict__ rope,
    u16* __restrict__ Qr, u16* __restrict__ Kr, u16* __restrict__ Vrt)
{
    const int n0 = blockIdx.x * 64, m0 = blockIdx.y * 64;
    const int zone = (n0 < 1024) ? 0 : (n0 < 1280) ? 1 : 2;
    const u16* __restrict__ Az = (zone == 0) ? Xq : (zone == 1) ? Xk : Xv;

    __shared__ short As[2][64][72];
    __shared__ short Bs[2][64][72];

    const int t = threadIdx.x;
    const int w = t >> 6, lane = t & 63, lm = lane & 15, quad = lane >> 4;
    const int sr = t >> 2, sc = (t & 3) * 16;

    f32x4 acc[4] = { {0,0,0,0}, {0,0,0,0}, {0,0,0,0}, {0,0,0,0} };

    const u16* ap_ = Az + (size_t)(m0 + sr) * DM + sc;
    const u16* bp_ = Wt + (size_t)(n0 + sr) * DM + sc;
    bf16x8 aR0 = *reinterpret_cast<const bf16x8*>(ap_);
    bf16x8 aR1 = *reinterpret_cast<const bf16x8*>(ap_ + 8);
    bf16x8 bR0 = *reinterpret_cast<const bf16x8*>(bp_);
    bf16x8 bR1 = *reinterpret_cast<const bf16x8*>(bp_ + 8);

    for (int k0 = 0; k0 < DM; k0 += 64) {
        const int buf = (k0 >> 6) & 1;
        *reinterpret_cast<bf16x8*>(&As[buf][sr][sc])     = aR0;
        *reinterpret_cast<bf16x8*>(&As[buf][sr][sc + 8]) = aR1;
        *reinterpret_cast<bf16x8*>(&Bs[buf][sr][sc])     = bR0;
        *reinterpret_cast<bf16x8*>(&Bs[buf][sr][sc + 8]) = bR1;
        if (k0 + 64 < DM) {
            aR0 = *reinterpret_cast<const bf16x8*>(ap_ + k0 + 64);
            aR1 = *reinterpret_cast<const bf16x8*>(ap_ + k0 + 72);
            bR0 = *reinterpret_cast<const bf16x8*>(bp_ + k0 + 64);
            bR1 = *reinterpret_cast<const bf16x8*>(bp_ + k0 + 72);
        }
        __syncthreads();
        bf16x8 af0 = *reinterpret_cast<const bf16x8*>(&As[buf][16 * w + lm][quad * 8]);
        bf16x8 af1 = *reinterpret_cast<const bf16x8*>(&As[buf][16 * w + lm][32 + quad * 8]);
        #pragma unroll
        for (int nb = 0; nb < 4; ++nb) {
            bf16x8 b0 = *reinterpret_cast<const bf16x8*>(&Bs[buf][16 * nb + lm][quad * 8]);
            bf16x8 b1 = *reinterpret_cast<const bf16x8*>(&Bs[buf][16 * nb + lm][32 + quad * 8]);
            acc[nb] = __builtin_amdgcn_mfma_f32_16x16x32_bf16(af0, b0, acc[nb], 0, 0, 0);
            acc[nb] = __builtin_amdgcn_mfma_f32_16x16x32_bf16(af1, b1, acc[nb], 0, 0, 0);
        }
        __syncthreads();
    }

    const float* __restrict__ bias = (zone == 0) ? bq : (zone == 1) ? bk : bv;
    const int nbase = (zone == 0) ? n0 : (zone == 1) ? (n0 - 1024) : (n0 - 1280);
    const int head = nbase >> 6;
    #pragma unroll
    for (int nb = 0; nb < 4; ++nb) {
        const int d = 16 * nb + lm;
        const float bvv = bias[nbase + d];
        float vals[4];
        #pragma unroll
        for (int r = 0; r < 4; ++r) vals[r] = acc[nb][r] + bvv;
        if (zone != 2) {
            const int pi = d >> 1;
            const bool odd = (lm & 1);
            const float sca = (zone == 0) ? QSCALE : 1.0f;
            u16* op = (zone == 0 ? Qr : Kr) + (size_t)head * SEQ * HD;
            #pragma unroll
            for (int r = 0; r < 4; ++r) {
                const int m = m0 + 16 * w + quad * 4 + r;
                const float2 cs2 = rope[(size_t)m * 32 + pi];   // {cos, sin}
                float x  = vals[r];
                float xp = __shfl_xor(x, 1);
                float o  = (odd ? (xp * cs2.y + x * cs2.x)
                                : (x * cs2.x - xp * cs2.y)) * sca;
                op[(size_t)m * HD + d] = f2b(o);
            }
        } else {
            // V transposed [kvh][d][pos], key-PERMUTED within each 64-tile:
            // within = m&63 -> pos = tile*64 + 4*(within&15) + (within>>4)
            u16* vp = Vrt + ((size_t)head * HD + d) * SEQ;
            #pragma unroll
            for (int r = 0; r < 4; ++r) {
                const int m = m0 + 16 * w + quad * 4 + r;
                const int within = m & 63;
                const int pos = (m & ~63) + 4 * (within & 15) + (within >> 4);
                vp[pos] = f2b(vals[r]);
            }
        }
    }
}

// ---------------------------------------------------------------- attention
// grid (16 heads, 16 qy), 256 threads (4 waves = 2 teams x 2 waves).
// Team 0 (waves 0,1): q-tile qy; team 1 (waves 2,3): q-tile 31-qy
// (constant 66 wave-steps/block). Each wave owns 32 q-rows (two 16-row
// MFMA A-frag sets) -> K/V fragment LDS reads amortized over 2x work.
// K/V staged once per kt for both teams (dbuf, 1 barrier/tile, reg prefetch).
// P: packed col-permuted LDS (c = 4*lm + nb) -> ds_write_b64; V global
// layout is key-permuted to match. Fixed-base exp2 softmax.
__global__ __launch_bounds__(256) void attn_mfma(
    const u16* __restrict__ Qr, const u16* __restrict__ Kr, const u16* __restrict__ Vrt,
    u16* __restrict__ AO)
{
    const int h  = blockIdx.x;
    const int qy = blockIdx.y;
    const int kvh = h & 3;

    __shared__ u16 Ks[2][64][72];     // [key][d]
    __shared__ u16 Vt[2][64][72];     // [d][c]  (c = permuted key)
    __shared__ u16 Ps[4][32][76];     // per-wave strip (32 q-rows); also Q staging

    const int t = threadIdx.x;
    const int w = t >> 6, lane = t & 63, lm = lane & 15, quad = lane >> 4;
    const int team = w >> 1, tw = w & 1;          // team: waves {0,1} / {2,3}
    const int qt  = team ? (31 - qy) : qy;
    const int qtb = 31 - qy;                      // = max(qt of both teams)

    {   // stage this wave's 32 Q rows into its Ps strip (wave-private)
        const int row = lane & 31, cb = (lane >> 5) * 32;
        const u16* qp = Qr + ((size_t)h * SEQ + qt * 64 + tw * 32 + row) * HD + cb;
        #pragma unroll
        for (int i = 0; i < 4; ++i)
            *reinterpret_cast<bf16x8*>(&Ps[w][row][cb + 8 * i]) =
                *reinterpret_cast<const bf16x8*>(qp + 8 * i);
    }
    bf16x8 aq[2][2];
    #pragma unroll
    for (int qb = 0; qb < 2; ++qb) {
        aq[qb][0] = *reinterpret_cast<const bf16x8*>(&Ps[w][16 * qb + lm][quad * 8]);
        aq[qb][1] = *reinterpret_cast<const bf16x8*>(&Ps[w][16 * qb + lm][32 + quad * 8]);
    }

    f32x4 O[2][4] = { { {0,0,0,0}, {0,0,0,0}, {0,0,0,0}, {0,0,0,0} },
                      { {0,0,0,0}, {0,0,0,0}, {0,0,0,0}, {0,0,0,0} } };
    float lp[2][4] = { {0.f,0.f,0.f,0.f}, {0.f,0.f,0.f,0.f} };

    // staging: 256 threads, 2 b128 each for K and V
    const int srow = t >> 2, sc2 = (t & 3) * 16;
    const u16* kb_ = Kr  + ((size_t)kvh * SEQ + srow) * HD + sc2;   // + kt*64*HD
    const u16* vb_ = Vrt + ((size_t)kvh * HD + srow) * SEQ + sc2;   // + kt*64
    bf16x8 kR0 = *reinterpret_cast<const bf16x8*>(kb_);
    bf16x8 kR1 = *reinterpret_cast<const bf16x8*>(kb_ + 8);
    bf16x8 vR0 = *reinterpret_cast<const bf16x8*>(vb_);
    bf16x8 vR1 = *reinterpret_cast<const bf16x8*>(vb_ + 8);

    for (int kt = 0; kt <= qtb; ++kt) {
        const int buf = kt & 1;
        *reinterpret_cast<bf16x8*>(&Ks[buf][srow][sc2])     = kR0;
        *reinterpret_cast<bf16x8*>(&Ks[buf][srow][sc2 + 8]) = kR1;
        *reinterpret_cast<bf16x8*>(&Vt[buf][srow][sc2])     = vR0;
        *reinterpret_cast<bf16x8*>(&Vt[buf][srow][sc2 + 8]) = vR1;
        if (kt < qtb) {
            kR0 = *reinterpret_cast<const bf16x8*>(kb_ + (size_t)(kt + 1) * 64 * HD);
            kR1 = *reinterpret_cast<const bf16x8*>(kb_ + (size_t)(kt + 1) * 64 * HD + 8);
            vR0 = *reinterpret_cast<const bf16x8*>(vb_ + (size_t)(kt + 1) * 64);
            vR1 = *reinterpret_cast<const bf16x8*>(vb_ + (size_t)(kt + 1) * 64 + 8);
        }
        __syncthreads();

        if (kt <= qt) {
            f32x4 s[2][4];
            #pragma unroll
            for (int nb = 0; nb < 4; ++nb) {
                bf16x8 b0 = *reinterpret_cast<const bf16x8*>(&Ks[buf][16 * nb + lm][quad * 8]);
                bf16x8 b1 = *reinterpret_cast<const bf16x8*>(&Ks[buf][16 * nb + lm][32 + quad * 8]);
                #pragma unroll
                for (int qb = 0; qb < 2; ++qb) {
                    f32x4 zz = { 0.f, 0.f, 0.f, 0.f };
                    zz = __builtin_amdgcn_mfma_f32_16x16x32_bf16(aq[qb][0], b0, zz, 0, 0, 0);
                    s[qb][nb] = __builtin_amdgcn_mfma_f32_16x16x32_bf16(aq[qb][1], b1, zz, 0, 0, 0);
                }
            }

            if (kt == qt) {   // causal mask (col=16nb+lm, row=32tw+16qb+quad*4+r)
                #pragma unroll
                for (int qb = 0; qb < 2; ++qb)
                    #pragma unroll
                    for (int nb = 0; nb < 4; ++nb)
                        #pragma unroll
                        for (int r = 0; r < 4; ++r)
                            if (16 * nb + lm > 32 * tw + 16 * qb + quad * 4 + r)
                                s[qb][nb][r] = -INFINITY;
            }

            // exp2 + packed P write: row 16qb+quad*4+r, cols c=4*lm..4*lm+3 (nb)
            #pragma unroll
            for (int qb = 0; qb < 2; ++qb)
                #pragma unroll
                for (int r = 0; r < 4; ++r) {
                    u16 pk[4];
                    #pragma unroll
                    for (int nb = 0; nb < 4; ++nb) {
                        float e = __builtin_amdgcn_exp2f(fminf(s[qb][nb][r], 126.f));
                        lp[qb][r] += e;
                        pk[nb] = f2b_fast(e);
                    }
                    *reinterpret_cast<uint2*>(&Ps[w][16 * qb + quad * 4 + r][4 * lm]) =
                        *reinterpret_cast<uint2*>(pk);
                }

            bf16x8 ap[2][2];
            #pragma unroll
            for (int qb = 0; qb < 2; ++qb) {
                ap[qb][0] = *reinterpret_cast<const bf16x8*>(&Ps[w][16 * qb + lm][quad * 8]);
                ap[qb][1] = *reinterpret_cast<const bf16x8*>(&Ps[w][16 * qb + lm][32 + quad * 8]);
            }
            #pragma unroll
            for (int db = 0; db < 4; ++db) {
                bf16x8 v0 = *reinterpret_cast<const bf16x8*>(&Vt[buf][16 * db + lm][quad * 8]);
                bf16x8 v1 = *reinterpret_cast<const bf16x8*>(&Vt[buf][16 * db + lm][32 + quad * 8]);
                #pragma unroll
                for (int qb = 0; qb < 2; ++qb) {
                    O[qb][db] = __builtin_amdgcn_mfma_f32_16x16x32_bf16(ap[qb][0], v0, O[qb][db], 0, 0, 0);
                    O[qb][db] = __builtin_amdgcn_mfma_f32_16x16x32_bf16(ap[qb][1], v1, O[qb][db], 0, 0, 0);
                }
            }
        }
    }

    #pragma unroll
    for (int qb = 0; qb < 2; ++qb)
        #pragma unroll
        for (int r = 0; r < 4; ++r) {
            #pragma unroll
            for (int off = 1; off < 16; off <<= 1)
                lp[qb][r] += __shfl_xor(lp[qb][r], off);
            const float inv = 1.0f / lp[qb][r];
            const size_t row = (size_t)(qt * 64 + 32 * tw + 16 * qb + quad * 4 + r) * DM
                             + (size_t)h * HD;
            #pragma unroll
            for (int db = 0; db < 4; ++db)
                AO[row + 16 * db + lm] = f2b(O[qb][db][r] * inv);
        }
}

// ---------------------------------------------------------------- output proj
// grid (16, 32): AO bf16 @ Wo^T bf16 + bo -> fp32 out. BK=64, dbuf + prefetch.
__global__ __launch_bounds__(256) void oproj_mfma(
    const u16* __restrict__ AO, const u16* __restrict__ wot,
    const float* __restrict__ bo, float* __restrict__ out)
{
    __shared__ short As[2][64][72];
    __shared__ short Bs[2][64][72];
    const int t = threadIdx.x;
    const int w = t >> 6, lane = t & 63, lm = lane & 15, quad = lane >> 4;
    const int m0 = blockIdx.y * 64, n0 = blockIdx.x * 64;
    const int sr = t >> 2, sc = (t & 3) * 16;

    f32x4 acc[4] = { {0,0,0,0}, {0,0,0,0}, {0,0,0,0}, {0,0,0,0} };

    const u16* ap_ = AO  + (size_t)(m0 + sr) * DM + sc;
    const u16* bp_ = wot + (size_t)(n0 + sr) * DM + sc;
    bf16x8 aR0 = *reinterpret_cast<const bf16x8*>(ap_);
    bf16x8 aR1 = *reinterpret_cast<const bf16x8*>(ap_ + 8);
    bf16x8 bR0 = *reinterpret_cast<const bf16x8*>(bp_);
    bf16x8 bR1 = *reinterpret_cast<const bf16x8*>(bp_ + 8);

    for (int k0 = 0; k0 < DM; k0 += 64) {
        const int buf = (k0 >> 6) & 1;
        *reinterpret_cast<bf16x8*>(&As[buf][sr][sc])     = aR0;
        *reinterpret_cast<bf16x8*>(&As[buf][sr][sc + 8]) = aR1;
        *reinterpret_cast<bf16x8*>(&Bs[buf][sr][sc])     = bR0;
        *reinterpret_cast<bf16x8*>(&Bs[buf][sr][sc + 8]) = bR1;
        if (k0 + 64 < DM) {
            aR0 = *reinterpret_cast<const bf16x8*>(ap_ + k0 + 64);
            aR1 = *reinterpret_cast<const bf16x8*>(ap_ + k0 + 72);
            bR0 = *reinterpret_cast<const bf16x8*>(bp_ + k0 + 64);
            bR1 = *reinterpret_cast<const bf16x8*>(bp_ + k0 + 72);
        }
        __syncthreads();
        bf16x8 af0 = *reinterpret_cast<const bf16x8*>(&As[buf][16 * w + lm][quad * 8]);
        bf16x8 af1 = *reinterpret_cast<const bf16x8*>(&As[buf][16 * w + lm][32 + quad * 8]);
        #pragma unroll
        for (int nb = 0; nb < 4; ++nb) {
            bf16x8 b0 = *reinterpret_cast<const bf16x8*>(&Bs[buf][16 * nb + lm][quad * 8]);
            bf16x8 b1 = *reinterpret_cast<const bf16x8*>(&Bs[buf][16 * nb + lm][32 + quad * 8]);
            acc[nb] = __builtin_amdgcn_mfma_f32_16x16x32_bf16(af0, b0, acc[nb], 0, 0, 0);
            acc[nb] = __builtin_amdgcn_mfma_f32_16x16x32_bf16(af1, b1, acc[nb], 0, 0, 0);
        }
        __syncthreads();
    }

    #pragma unroll
    for (int nb = 0; nb < 4; ++nb) {
        const int dl = 16 * nb + lm;
        const float bv = bo[n0 + dl];
        #pragma unroll
        for (int r = 0; r < 4; ++r) {
            const int m = m0 + 16 * w + quad * 4 + r;
            out[(size_t)m * DM + n0 + dl] = acc[nb][r] + bv;
        }
    }
}

// ---------------------------------------------------------------- launcher
extern "C" void kernel_launch(void* const* d_in, const int* in_sizes, int n_in,
                              void* d_out, int out_size, void* d_ws, size_t ws_size,
                              hipStream_t stream)
{
    const float* q  = (const float*)d_in[0];
    const float* k  = (const float*)d_in[1];
    const float* v  = (const float*)d_in[2];
    // d_in[3] = mask (int32) — causal tril, handled analytically
    const float* Wq = (const float*)d_in[4];
    const float* bq = (const float*)d_in[5];
    const float* Wk = (const float*)d_in[6];
    const float* bk = (const float*)d_in[7];
    const float* Wv = (const float*)d_in[8];
    const float* bv = (const float*)d_in[9];
    const float* Wo = (const float*)d_in[10];
    const float* bo = (const float*)d_in[11];
    float* out = (float*)d_out;

    u16* Xq  = (u16*)d_ws;                          // [2048][1024] bf16
    u16* Xk  = Xq  + (size_t)SEQ * DM;
    u16* Xv  = Xk  + (size_t)SEQ * DM;
    u16* Wt  = Xv  + (size_t)SEQ * DM;              // [1536][1024]
    u16* wot = Wt  + (size_t)1536 * 1024;           // [1024][1024]
    u16* Qr  = wot + (size_t)1024 * 1024;           // [16][2048][64]
    u16* Kr  = Qr  + (size_t)16 * SEQ * HD;         // [4][2048][64]
    u16* Vrt = Kr  + (size_t)4 * SEQ * HD;          // [4][64][2048] key-permuted
    u16* AO  = Vrt + (size_t)4 * SEQ * HD;          // [2048][1024]
    float2* rope = (float2*)(AO + (size_t)SEQ * DM); // [2048][32] {cos,sin} f32

    hipLaunchKernelGGL(prep_kernel, dim3(1416), dim3(256), 0, stream,
                       q, k, v, Wq, Wk, Wv, Wo, Xq, Xk, Xv, Wt, wot, rope);
    hipLaunchKernelGGL(proj_mfma, dim3(24, 32), dim3(256), 0, stream,
                       Xq, Xk, Xv, Wt, bq, bk, bv, rope, Qr, Kr, Vrt);
    hipLaunchKernelGGL(attn_mfma, dim3(16, 16), dim3(256), 0, stream,
                       Qr, Kr, Vrt, AO);
    hipLaunchKernelGGL(oproj_mfma, dim3(16, 32), dim3(256), 0, stream,
                       AO, wot, bo, out);
}

// Round 3
// 166.008 us; speedup vs baseline: 1.0888x; 1.0888x over previous
//
#include <hip/hip_runtime.h>
#include <hip/hip_bf16.h>
#include <math.h>

// GQA attention forward, MI355X. Round 12: attn occupancy restore.
//  - attn: 512 blocks x 256 thr (4 waves x 16 q-rows, r9 per-wave shape).
//    One 64-row q-tile per block; causal balance via constant-sum pairing
//    (bid<256: qt=bid>>4, else qt=31-((bid-256)>>4)) so CU slots under the
//    XCD round-robin get qt pairs summing to 31 (34 tile-steps/CU).
//    LDS 45.5KB -> 2-3 blocks/CU => >=2 waves/SIMD with independent
//    barrier groups (r11's 1 wave/SIMD was pure latency-bound: MfmaUtil 6.7%).
//  - prep/proj/oproj unchanged (RoPE table kept).
// ws (u16): Xq 2M | Xk 2M | Xv 2M | Wt 1.5M | wot 1M | Qr 2M | Kr 512K | Vrt 512K | AO 2M | rope 512KB(f32)

#define SEQ 2048
#define DM 1024
#define HD 64

using u16 = unsigned short;
typedef __attribute__((ext_vector_type(8))) short bf16x8;
typedef __attribute__((ext_vector_type(4))) float f32x4;

// 1/sqrt(64) * log2(e): softmax in exp2 domain.
#define QSCALE 0.18033688011112042f

__device__ __forceinline__ u16 f2b(float f) {              // RNE
    union { float f; unsigned int i; } v; v.f = f;
    unsigned int u = v.i;
    return (u16)((u + 0x7fffu + ((u >> 16) & 1u)) >> 16);
}
__device__ __forceinline__ u16 f2b_fast(float f) {         // biased round
    union { float f; unsigned int i; } v; v.f = f;
    return (u16)((v.i + 0x8000u) >> 16);
}

// ---------------------------------------------------------------- prep
// [0,640): weight 64x64 transposes fp32->bf16 row-major [n][k].
// [640,1408): q/k/v fp32 -> bf16 row-major.
// [1408,1416): RoPE table rope[m][pi] = {cos(m*theta_pi), sin(m*theta_pi)}.
__global__ __launch_bounds__(256) void prep_kernel(
    const float* __restrict__ qin, const float* __restrict__ kin, const float* __restrict__ vin,
    const float* __restrict__ Wq, const float* __restrict__ Wk,
    const float* __restrict__ Wv, const float* __restrict__ Wo,
    u16* __restrict__ Xq, u16* __restrict__ Xk, u16* __restrict__ Xv,
    u16* __restrict__ Wt, u16* __restrict__ wot, float2* __restrict__ rope)
{
    const int b = blockIdx.x;
    const int t = threadIdx.x;

    if (b < 640) {
        __shared__ short T[64][72];
        const float* W; u16* dst; int N, t0, rowoff;
        if (b < 256)      { W = Wq; dst = Wt;  N = 1024; t0 = b;       rowoff = 0; }
        else if (b < 320) { W = Wk; dst = Wt;  N = 256;  t0 = b - 256; rowoff = 1024; }
        else if (b < 384) { W = Wv; dst = Wt;  N = 256;  t0 = b - 320; rowoff = 1280; }
        else              { W = Wo; dst = wot; N = 1024; t0 = b - 384; rowoff = 0; }
        const int ntn = N >> 6;
        const int k0 = (t0 / ntn) * 64, n0 = (t0 % ntn) * 64;
        const int r = t >> 4, c4 = (t & 15) * 4;
        #pragma unroll
        for (int rr = 0; rr < 4; ++rr) {
            const int k = r + rr * 16;
            float4 w4 = *reinterpret_cast<const float4*>(W + (size_t)(k0 + k) * N + n0 + c4);
            T[c4 + 0][k] = (short)f2b(w4.x);
            T[c4 + 1][k] = (short)f2b(w4.y);
            T[c4 + 2][k] = (short)f2b(w4.z);
            T[c4 + 3][k] = (short)f2b(w4.w);
        }
        __syncthreads();
        const int n = t >> 2, ck = (t & 3) * 16;
        u16* dp = dst + (size_t)(rowoff + n0 + n) * DM + k0 + ck;
        *reinterpret_cast<bf16x8*>(dp)     = *reinterpret_cast<const bf16x8*>(&T[n][ck]);
        *reinterpret_cast<bf16x8*>(dp + 8) = *reinterpret_cast<const bf16x8*>(&T[n][ck + 8]);
    } else if (b < 1408) {
        const int idx = b - 640;
        const int which = idx >> 8;
        const int ib = idx & 255;
        const float* src = (which == 0) ? qin : (which == 1) ? kin : vin;
        u16* dst = (which == 0) ? Xq : (which == 1) ? Xk : Xv;
        const size_t base = (size_t)ib * 8192 + (size_t)t * 32;
        #pragma unroll
        for (int c = 0; c < 4; ++c) {
            float4 x0 = *reinterpret_cast<const float4*>(src + base + c * 8);
            float4 x1 = *reinterpret_cast<const float4*>(src + base + c * 8 + 4);
            bf16x8 o;
            o[0] = (short)f2b(x0.x); o[1] = (short)f2b(x0.y);
            o[2] = (short)f2b(x0.z); o[3] = (short)f2b(x0.w);
            o[4] = (short)f2b(x1.x); o[5] = (short)f2b(x1.y);
            o[6] = (short)f2b(x1.z); o[7] = (short)f2b(x1.w);
            *reinterpret_cast<bf16x8*>(dst + base + c * 8) = o;
        }
    } else {
        // RoPE table: one thread per position m, 32 (cos,sin) pairs each.
        const int m = (b - 1408) * 256 + t;
        float2* rp = rope + (size_t)m * 32;
        for (int pi = 0; pi < 32; ++pi) {
            const float theta = exp2f(-0.8304820237f * (float)pi);  // 10000^(-pi/16)
            float sn, cs;
            sincosf((float)m * theta, &sn, &cs);
            rp[pi] = make_float2(cs, sn);
        }
    }
}

// ---------------------------------------------------------------- projections
// Unified QKV: grid (24, 32), 64x64 tile, BK=64, dbuf + reg prefetch,
// 1 barrier/iter. Cols [0,1024)=Q (RoPE*QSCALE), [1024,1280)=K (RoPE),
// [1280,1536)=V (transposed + key-permuted store).
__global__ __launch_bounds__(256) void proj_mfma(
    const u16* __restrict__ Xq, const u16* __restrict__ Xk, const u16* __restrict__ Xv,
    const u16* __restrict__ Wt,
    const float* __restrict__ bq, const float* __restrict__ bk, const float* __restrict__ bv,
    const float2* __restrict__ rope,
    u16* __restrict__ Qr, u16* __restrict__ Kr, u16* __restrict__ Vrt)
{
    const int n0 = blockIdx.x * 64, m0 = blockIdx.y * 64;
    const int zone = (n0 < 1024) ? 0 : (n0 < 1280) ? 1 : 2;
    const u16* __restrict__ Az = (zone == 0) ? Xq : (zone == 1) ? Xk : Xv;

    __shared__ short As[2][64][72];
    __shared__ short Bs[2][64][72];

    const int t = threadIdx.x;
    const int w = t >> 6, lane = t & 63, lm = lane & 15, quad = lane >> 4;
    const int sr = t >> 2, sc = (t & 3) * 16;

    f32x4 acc[4] = { {0,0,0,0}, {0,0,0,0}, {0,0,0,0}, {0,0,0,0} };

    const u16* ap_ = Az + (size_t)(m0 + sr) * DM + sc;
    const u16* bp_ = Wt + (size_t)(n0 + sr) * DM + sc;
    bf16x8 aR0 = *reinterpret_cast<const bf16x8*>(ap_);
    bf16x8 aR1 = *reinterpret_cast<const bf16x8*>(ap_ + 8);
    bf16x8 bR0 = *reinterpret_cast<const bf16x8*>(bp_);
    bf16x8 bR1 = *reinterpret_cast<const bf16x8*>(bp_ + 8);

    for (int k0 = 0; k0 < DM; k0 += 64) {
        const int buf = (k0 >> 6) & 1;
        *reinterpret_cast<bf16x8*>(&As[buf][sr][sc])     = aR0;
        *reinterpret_cast<bf16x8*>(&As[buf][sr][sc + 8]) = aR1;
        *reinterpret_cast<bf16x8*>(&Bs[buf][sr][sc])     = bR0;
        *reinterpret_cast<bf16x8*>(&Bs[buf][sr][sc + 8]) = bR1;
        if (k0 + 64 < DM) {
            aR0 = *reinterpret_cast<const bf16x8*>(ap_ + k0 + 64);
            aR1 = *reinterpret_cast<const bf16x8*>(ap_ + k0 + 72);
            bR0 = *reinterpret_cast<const bf16x8*>(bp_ + k0 + 64);
            bR1 = *reinterpret_cast<const bf16x8*>(bp_ + k0 + 72);
        }
        __syncthreads();
        bf16x8 af0 = *reinterpret_cast<const bf16x8*>(&As[buf][16 * w + lm][quad * 8]);
        bf16x8 af1 = *reinterpret_cast<const bf16x8*>(&As[buf][16 * w + lm][32 + quad * 8]);
        #pragma unroll
        for (int nb = 0; nb < 4; ++nb) {
            bf16x8 b0 = *reinterpret_cast<const bf16x8*>(&Bs[buf][16 * nb + lm][quad * 8]);
            bf16x8 b1 = *reinterpret_cast<const bf16x8*>(&Bs[buf][16 * nb + lm][32 + quad * 8]);
            acc[nb] = __builtin_amdgcn_mfma_f32_16x16x32_bf16(af0, b0, acc[nb], 0, 0, 0);
            acc[nb] = __builtin_amdgcn_mfma_f32_16x16x32_bf16(af1, b1, acc[nb], 0, 0, 0);
        }
        __syncthreads();
    }

    const float* __restrict__ bias = (zone == 0) ? bq : (zone == 1) ? bk : bv;
    const int nbase = (zone == 0) ? n0 : (zone == 1) ? (n0 - 1024) : (n0 - 1280);
    const int head = nbase >> 6;
    #pragma unroll
    for (int nb = 0; nb < 4; ++nb) {
        const int d = 16 * nb + lm;
        const float bvv = bias[nbase + d];
        float vals[4];
        #pragma unroll
        for (int r = 0; r < 4; ++r) vals[r] = acc[nb][r] + bvv;
        if (zone != 2) {
            const int pi = d >> 1;
            const bool odd = (lm & 1);
            const float sca = (zone == 0) ? QSCALE : 1.0f;
            u16* op = (zone == 0 ? Qr : Kr) + (size_t)head * SEQ * HD;
            #pragma unroll
            for (int r = 0; r < 4; ++r) {
                const int m = m0 + 16 * w + quad * 4 + r;
                const float2 cs2 = rope[(size_t)m * 32 + pi];   // {cos, sin}
                float x  = vals[r];
                float xp = __shfl_xor(x, 1);
                float o  = (odd ? (xp * cs2.y + x * cs2.x)
                                : (x * cs2.x - xp * cs2.y)) * sca;
                op[(size_t)m * HD + d] = f2b(o);
            }
        } else {
            // V transposed [kvh][d][pos], key-PERMUTED within each 64-tile:
            // within = m&63 -> pos = tile*64 + 4*(within&15) + (within>>4)
            u16* vp = Vrt + ((size_t)head * HD + d) * SEQ;
            #pragma unroll
            for (int r = 0; r < 4; ++r) {
                const int m = m0 + 16 * w + quad * 4 + r;
                const int within = m & 63;
                const int pos = (m & ~63) + 4 * (within & 15) + (within >> 4);
                vp[pos] = f2b(vals[r]);
            }
        }
    }
}

// ---------------------------------------------------------------- attention
// 512 blocks x 256 threads (4 waves x 16 q-rows = one 64-row q-tile).
// Block -> (h, qt): h = bid & 15; qt = bid<256 ? bid>>4 : 31-((bid-256)>>4).
// Under XCD round-robin, CU slots receive bid and bid+256 whose qt sum to 31
// -> constant 34 tile-steps per CU. 45.5KB LDS -> 2-3 blocks/CU resident;
// independent barrier groups overlap each other's stalls.
// K/V dbuf staged per tile (1 barrier/tile, reg prefetch). P: packed
// col-permuted LDS (c = 4*lm + nb) -> ds_write_b64; V global layout is
// key-permuted to match. Fixed-base exp2 softmax.
__global__ __launch_bounds__(256) void attn_mfma(
    const u16* __restrict__ Qr, const u16* __restrict__ Kr, const u16* __restrict__ Vrt,
    u16* __restrict__ AO)
{
    const int bid = blockIdx.x;
    const int h  = bid & 15;
    const int qt = (bid < 256) ? (bid >> 4) : 31 - ((bid - 256) >> 4);
    const int kvh = h & 3;

    __shared__ u16 Ks[2][64][72];     // [key][d]
    __shared__ u16 Vt[2][64][72];     // [d][c]  (c = permuted key)
    __shared__ u16 Ps[4][16][76];     // per-wave strip; also Q staging

    const int t = threadIdx.x;
    const int w = t >> 6, lane = t & 63, lm = lane & 15, quad = lane >> 4;

    {   // stage this wave's 16 Q rows into its Ps strip (wave-private)
        const int row = lane >> 2, c = (lane & 3) * 16;
        const u16* qp = Qr + ((size_t)h * SEQ + qt * 64 + w * 16 + row) * HD + c;
        *reinterpret_cast<bf16x8*>(&Ps[w][row][c])     = *reinterpret_cast<const bf16x8*>(qp);
        *reinterpret_cast<bf16x8*>(&Ps[w][row][c + 8]) = *reinterpret_cast<const bf16x8*>(qp + 8);
    }
    const bf16x8 aq0 = *reinterpret_cast<const bf16x8*>(&Ps[w][lm][quad * 8]);
    const bf16x8 aq1 = *reinterpret_cast<const bf16x8*>(&Ps[w][lm][32 + quad * 8]);

    f32x4 O[4] = { {0,0,0,0}, {0,0,0,0}, {0,0,0,0}, {0,0,0,0} };   // C[q=quad*4+r][d=16db+lm]
    float lp[4] = { 0.f, 0.f, 0.f, 0.f };

    // staging: 256 threads, 2 b128 each for K and V
    const int srow = t >> 2, sc2 = (t & 3) * 16;
    const u16* kb_ = Kr  + ((size_t)kvh * SEQ + srow) * HD + sc2;   // + kt*64*HD
    const u16* vb_ = Vrt + ((size_t)kvh * HD + srow) * SEQ + sc2;   // + kt*64
    bf16x8 kR0 = *reinterpret_cast<const bf16x8*>(kb_);
    bf16x8 kR1 = *reinterpret_cast<const bf16x8*>(kb_ + 8);
    bf16x8 vR0 = *reinterpret_cast<const bf16x8*>(vb_);
    bf16x8 vR1 = *reinterpret_cast<const bf16x8*>(vb_ + 8);

    for (int kt = 0; kt <= qt; ++kt) {
        const int buf = kt & 1;
        *reinterpret_cast<bf16x8*>(&Ks[buf][srow][sc2])     = kR0;
        *reinterpret_cast<bf16x8*>(&Ks[buf][srow][sc2 + 8]) = kR1;
        *reinterpret_cast<bf16x8*>(&Vt[buf][srow][sc2])     = vR0;
        *reinterpret_cast<bf16x8*>(&Vt[buf][srow][sc2 + 8]) = vR1;
        if (kt < qt) {
            kR0 = *reinterpret_cast<const bf16x8*>(kb_ + (size_t)(kt + 1) * 64 * HD);
            kR1 = *reinterpret_cast<const bf16x8*>(kb_ + (size_t)(kt + 1) * 64 * HD + 8);
            vR0 = *reinterpret_cast<const bf16x8*>(vb_ + (size_t)(kt + 1) * 64);
            vR1 = *reinterpret_cast<const bf16x8*>(vb_ + (size_t)(kt + 1) * 64 + 8);
        }
        __syncthreads();

        f32x4 s[4];
        #pragma unroll
        for (int nb = 0; nb < 4; ++nb) {
            bf16x8 b0 = *reinterpret_cast<const bf16x8*>(&Ks[buf][16 * nb + lm][quad * 8]);
            bf16x8 b1 = *reinterpret_cast<const bf16x8*>(&Ks[buf][16 * nb + lm][32 + quad * 8]);
            f32x4 zz = { 0.f, 0.f, 0.f, 0.f };
            zz = __builtin_amdgcn_mfma_f32_16x16x32_bf16(aq0, b0, zz, 0, 0, 0);
            s[nb] = __builtin_amdgcn_mfma_f32_16x16x32_bf16(aq1, b1, zz, 0, 0, 0);
        }

        if (kt == qt) {   // causal mask (col=16nb+lm, row=16w+quad*4+r)
            #pragma unroll
            for (int nb = 0; nb < 4; ++nb)
                #pragma unroll
                for (int r = 0; r < 4; ++r)
                    if (16 * nb + lm > 16 * w + quad * 4 + r) s[nb][r] = -INFINITY;
        }

        // exp2 + packed P write: row quad*4+r, cols c=4*lm..4*lm+3 (nb)
        #pragma unroll
        for (int r = 0; r < 4; ++r) {
            u16 pk[4];
            #pragma unroll
            for (int nb = 0; nb < 4; ++nb) {
                float e = __builtin_amdgcn_exp2f(fminf(s[nb][r], 126.f));
                lp[r] += e;
                pk[nb] = f2b_fast(e);
            }
            *reinterpret_cast<uint2*>(&Ps[w][quad * 4 + r][4 * lm]) =
                *reinterpret_cast<uint2*>(pk);
        }

        const bf16x8 ap0 = *reinterpret_cast<const bf16x8*>(&Ps[w][lm][quad * 8]);
        const bf16x8 ap1 = *reinterpret_cast<const bf16x8*>(&Ps[w][lm][32 + quad * 8]);
        #pragma unroll
        for (int db = 0; db < 4; ++db) {
            bf16x8 v0 = *reinterpret_cast<const bf16x8*>(&Vt[buf][16 * db + lm][quad * 8]);
            bf16x8 v1 = *reinterpret_cast<const bf16x8*>(&Vt[buf][16 * db + lm][32 + quad * 8]);
            O[db] = __builtin_amdgcn_mfma_f32_16x16x32_bf16(ap0, v0, O[db], 0, 0, 0);
            O[db] = __builtin_amdgcn_mfma_f32_16x16x32_bf16(ap1, v1, O[db], 0, 0, 0);
        }
    }

    #pragma unroll
    for (int r = 0; r < 4; ++r) {
        #pragma unroll
        for (int off = 1; off < 16; off <<= 1)
            lp[r] += __shfl_xor(lp[r], off);
        const float inv = 1.0f / lp[r];
        const size_t row = (size_t)(qt * 64 + 16 * w + quad * 4 + r) * DM + (size_t)h * HD;
        #pragma unroll
        for (int db = 0; db < 4; ++db)
            AO[row + 16 * db + lm] = f2b(O[db][r] * inv);
    }
}

// ---------------------------------------------------------------- output proj
// grid (16, 32): AO bf16 @ Wo^T bf16 + bo -> fp32 out. BK=64, dbuf + prefetch.
__global__ __launch_bounds__(256) void oproj_mfma(
    const u16* __restrict__ AO, const u16* __restrict__ wot,
    const float* __restrict__ bo, float* __restrict__ out)
{
    __shared__ short As[2][64][72];
    __shared__ short Bs[2][64][72];
    const int t = threadIdx.x;
    const int w = t >> 6, lane = t & 63, lm = lane & 15, quad = lane >> 4;
    const int m0 = blockIdx.y * 64, n0 = blockIdx.x * 64;
    const int sr = t >> 2, sc = (t & 3) * 16;

    f32x4 acc[4] = { {0,0,0,0}, {0,0,0,0}, {0,0,0,0}, {0,0,0,0} };

    const u16* ap_ = AO  + (size_t)(m0 + sr) * DM + sc;
    const u16* bp_ = wot + (size_t)(n0 + sr) * DM + sc;
    bf16x8 aR0 = *reinterpret_cast<const bf16x8*>(ap_);
    bf16x8 aR1 = *reinterpret_cast<const bf16x8*>(ap_ + 8);
    bf16x8 bR0 = *reinterpret_cast<const bf16x8*>(bp_);
    bf16x8 bR1 = *reinterpret_cast<const bf16x8*>(bp_ + 8);

    for (int k0 = 0; k0 < DM; k0 += 64) {
        const int buf = (k0 >> 6) & 1;
        *reinterpret_cast<bf16x8*>(&As[buf][sr][sc])     = aR0;
        *reinterpret_cast<bf16x8*>(&As[buf][sr][sc + 8]) = aR1;
        *reinterpret_cast<bf16x8*>(&Bs[buf][sr][sc])     = bR0;
        *reinterpret_cast<bf16x8*>(&Bs[buf][sr][sc + 8]) = bR1;
        if (k0 + 64 < DM) {
            aR0 = *reinterpret_cast<const bf16x8*>(ap_ + k0 + 64);
            aR1 = *reinterpret_cast<const bf16x8*>(ap_ + k0 + 72);
            bR0 = *reinterpret_cast<const bf16x8*>(bp_ + k0 + 64);
            bR1 = *reinterpret_cast<const bf16x8*>(bp_ + k0 + 72);
        }
        __syncthreads();
        bf16x8 af0 = *reinterpret_cast<const bf16x8*>(&As[buf][16 * w + lm][quad * 8]);
        bf16x8 af1 = *reinterpret_cast<const bf16x8*>(&As[buf][16 * w + lm][32 + quad * 8]);
        #pragma unroll
        for (int nb = 0; nb < 4; ++nb) {
            bf16x8 b0 = *reinterpret_cast<const bf16x8*>(&Bs[buf][16 * nb + lm][quad * 8]);
            bf16x8 b1 = *reinterpret_cast<const bf16x8*>(&Bs[buf][16 * nb + lm][32 + quad * 8]);
            acc[nb] = __builtin_amdgcn_mfma_f32_16x16x32_bf16(af0, b0, acc[nb], 0, 0, 0);
            acc[nb] = __builtin_amdgcn_mfma_f32_16x16x32_bf16(af1, b1, acc[nb], 0, 0, 0);
        }
        __syncthreads();
    }

    #pragma unroll
    for (int nb = 0; nb < 4; ++nb) {
        const int dl = 16 * nb + lm;
        const float bv = bo[n0 + dl];
        #pragma unroll
        for (int r = 0; r < 4; ++r) {
            const int m = m0 + 16 * w + quad * 4 + r;
            out[(size_t)m * DM + n0 + dl] = acc[nb][r] + bv;
        }
    }
}

// ---------------------------------------------------------------- launcher
extern "C" void kernel_launch(void* const* d_in, const int* in_sizes, int n_in,
                              void* d_out, int out_size, void* d_ws, size_t ws_size,
                              hipStream_t stream)
{
    const float* q  = (const float*)d_in[0];
    const float* k  = (const float*)d_in[1];
    const float* v  = (const float*)d_in[2];
    // d_in[3] = mask (int32) — causal tril, handled analytically
    const float* Wq = (const float*)d_in[4];
    const float* bq = (const float*)d_in[5];
    const float* Wk = (const float*)d_in[6];
    const float* bk = (const float*)d_in[7];
    const float* Wv = (const float*)d_in[8];
    const float* bv = (const float*)d_in[9];
    const float* Wo = (const float*)d_in[10];
    const float* bo = (const float*)d_in[11];
    float* out = (float*)d_out;

    u16* Xq  = (u16*)d_ws;                          // [2048][1024] bf16
    u16* Xk  = Xq  + (size_t)SEQ * DM;
    u16* Xv  = Xk  + (size_t)SEQ * DM;
    u16* Wt  = Xv  + (size_t)SEQ * DM;              // [1536][1024]
    u16* wot = Wt  + (size_t)1536 * 1024;           // [1024][1024]
    u16* Qr  = wot + (size_t)1024 * 1024;           // [16][2048][64]
    u16* Kr  = Qr  + (size_t)16 * SEQ * HD;         // [4][2048][64]
    u16* Vrt = Kr  + (size_t)4 * SEQ * HD;          // [4][64][2048] key-permuted
    u16* AO  = Vrt + (size_t)4 * SEQ * HD;          // [2048][1024]
    float2* rope = (float2*)(AO + (size_t)SEQ * DM); // [2048][32] {cos,sin} f32

    hipLaunchKernelGGL(prep_kernel, dim3(1416), dim3(256), 0, stream,
                       q, k, v, Wq, Wk, Wv, Wo, Xq, Xk, Xv, Wt, wot, rope);
    hipLaunchKernelGGL(proj_mfma, dim3(24, 32), dim3(256), 0, stream,
                       Xq, Xk, Xv, Wt, bq, bk, bv, rope, Qr, Kr, Vrt);
    hipLaunchKernelGGL(attn_mfma, dim3(512), dim3(256), 0, stream,
                       Qr, Kr, Vrt, AO);
    hipLaunchKernelGGL(oproj_mfma, dim3(16, 32), dim3(256), 0, stream,
                       AO, wot, bo, out);
}

// Round 5
// 165.407 us; speedup vs baseline: 1.0927x; 1.0036x over previous
//
#include <hip/hip_runtime.h>
#include <hip/hip_bf16.h>
#include <math.h>

// GQA attention forward, MI355X. Round 13 (resubmit after GPU acquisition
// timeout — no measurement happened): proj -> global_load_lds + swizzled tiles.
//  - Xq/Xk/Xv and Wt now stored as 64x64 bf16 tiles (8KB), byte-granule
//    XOR-swizzled: within a tile, (row r, 16B-granule g) lives at
//    r*128 + ((g ^ (r&7))<<4). prep writes this layout directly.
//  - proj: stages A/B tiles via __builtin_amdgcn_global_load_lds width=16
//    (linear LDS dest = pre-swizzled global src), ds_read_b128 frags with
//    the same XOR -> conflict-free, no staging ds_writes/VGPRs.
//    2-phase m97 pipeline: stage(next) -> compute(cur) -> __syncthreads.
//  - attn/oproj/wot/AO/Qr/Kr/Vrt unchanged from r12.
// ws (u16): Xq 2M | Xk 2M | Xv 2M | Wt 1.5M | wot 1M | Qr 2M | Kr 512K | Vrt 512K | AO 2M | rope 512KB(f32)

#define SEQ 2048
#define DM 1024
#define HD 64

using u16 = unsigned short;
typedef __attribute__((ext_vector_type(8))) short bf16x8;
typedef __attribute__((ext_vector_type(4))) float f32x4;

// 1/sqrt(64) * log2(e): softmax in exp2 domain.
#define QSCALE 0.18033688011112042f

__device__ __forceinline__ u16 f2b(float f) {              // RNE
    union { float f; unsigned int i; } v; v.f = f;
    unsigned int u = v.i;
    return (u16)((u + 0x7fffu + ((u >> 16) & 1u)) >> 16);
}
__device__ __forceinline__ u16 f2b_fast(float f) {         // biased round
    union { float f; unsigned int i; } v; v.f = f;
    return (u16)((v.i + 0x8000u) >> 16);
}

// ---------------------------------------------------------------- prep
// [0,640): weight 64x64 transposes fp32 -> bf16. b<384 -> Wt (tiled+swizzled),
//          else -> wot (row-major, oproj unchanged).
// [640,1408): q/k/v fp32 -> bf16, tiled+swizzled 64x64 layout.
// [1408,1416): RoPE table rope[m][pi] = {cos,sin}.
__global__ __launch_bounds__(256) void prep_kernel(
    const float* __restrict__ qin, const float* __restrict__ kin, const float* __restrict__ vin,
    const float* __restrict__ Wq, const float* __restrict__ Wk,
    const float* __restrict__ Wv, const float* __restrict__ Wo,
    u16* __restrict__ Xq, u16* __restrict__ Xk, u16* __restrict__ Xv,
    u16* __restrict__ Wt, u16* __restrict__ wot, float2* __restrict__ rope)
{
    const int b = blockIdx.x;
    const int t = threadIdx.x;

    if (b < 640) {
        __shared__ short T[64][72];
        const float* W; u16* dst; int N, t0, rowoff;
        if (b < 256)      { W = Wq; dst = Wt;  N = 1024; t0 = b;       rowoff = 0; }
        else if (b < 320) { W = Wk; dst = Wt;  N = 256;  t0 = b - 256; rowoff = 1024; }
        else if (b < 384) { W = Wv; dst = Wt;  N = 256;  t0 = b - 320; rowoff = 1280; }
        else              { W = Wo; dst = wot; N = 1024; t0 = b - 384; rowoff = 0; }
        const int ntn = N >> 6;
        const int k0 = (t0 / ntn) * 64, n0 = (t0 % ntn) * 64;
        const int r = t >> 4, c4 = (t & 15) * 4;
        #pragma unroll
        for (int rr = 0; rr < 4; ++rr) {
            const int k = r + rr * 16;
            float4 w4 = *reinterpret_cast<const float4*>(W + (size_t)(k0 + k) * N + n0 + c4);
            T[c4 + 0][k] = (short)f2b(w4.x);
            T[c4 + 1][k] = (short)f2b(w4.y);
            T[c4 + 2][k] = (short)f2b(w4.z);
            T[c4 + 3][k] = (short)f2b(w4.w);
        }
        __syncthreads();
        const int n = t >> 2, ck = (t & 3) * 16;
        if (b < 384) {
            // tiled + swizzled: tile (nt, kt), row n, granules g0, g0+1
            const int nt = (rowoff + n0) >> 6, kt = k0 >> 6;
            char* dp = (char*)(dst + (size_t)(nt * 16 + kt) * 4096) + n * 128;
            const int g0 = (t & 3) * 2, rx = n & 7;
            *reinterpret_cast<bf16x8*>(dp + (((g0    ) ^ rx) << 4)) =
                *reinterpret_cast<const bf16x8*>(&T[n][ck]);
            *reinterpret_cast<bf16x8*>(dp + (((g0 + 1) ^ rx) << 4)) =
                *reinterpret_cast<const bf16x8*>(&T[n][ck + 8]);
        } else {
            u16* dp = dst + (size_t)(n0 + n) * DM + k0 + ck;
            *reinterpret_cast<bf16x8*>(dp)     = *reinterpret_cast<const bf16x8*>(&T[n][ck]);
            *reinterpret_cast<bf16x8*>(dp + 8) = *reinterpret_cast<const bf16x8*>(&T[n][ck + 8]);
        }
    } else if (b < 1408) {
        const int idx = b - 640;
        const int which = idx >> 8;
        const int ib = idx & 255;
        const float* src = (which == 0) ? qin : (which == 1) ? kin : vin;
        u16* dst = (which == 0) ? Xq : (which == 1) ? Xk : Xv;
        const int m  = ib * 8 + (t >> 5);          // global row
        const int mt = m >> 6, r = m & 63, rx = r & 7;
        const int col0 = (t & 31) * 32;
        const float* sp = src + (size_t)m * 1024 + col0;
        #pragma unroll
        for (int c = 0; c < 4; ++c) {
            float4 x0 = *reinterpret_cast<const float4*>(sp + c * 8);
            float4 x1 = *reinterpret_cast<const float4*>(sp + c * 8 + 4);
            bf16x8 o;
            o[0] = (short)f2b(x0.x); o[1] = (short)f2b(x0.y);
            o[2] = (short)f2b(x0.z); o[3] = (short)f2b(x0.w);
            o[4] = (short)f2b(x1.x); o[5] = (short)f2b(x1.y);
            o[6] = (short)f2b(x1.z); o[7] = (short)f2b(x1.w);
            const int col = col0 + c * 8;
            const int kt = col >> 6, g = (col & 63) >> 3;
            char* dp = (char*)(dst + (size_t)(mt * 16 + kt) * 4096)
                     + r * 128 + ((g ^ rx) << 4);
            *reinterpret_cast<bf16x8*>(dp) = o;
        }
    } else {
        // RoPE table: one thread per position m, 32 (cos,sin) pairs each.
        const int m = (b - 1408) * 256 + t;
        float2* rp = rope + (size_t)m * 32;
        for (int pi = 0; pi < 32; ++pi) {
            const float theta = exp2f(-0.8304820237f * (float)pi);  // 10000^(-pi/16)
            float sn, cs;
            sincosf((float)m * theta, &sn, &cs);
            rp[pi] = make_float2(cs, sn);
        }
    }
}

// ---------------------------------------------------------------- projections
// Unified QKV: grid (24, 32), 64x64 tile, BK=64.
// Staging: global_load_lds width=16 from swizzled tiles (linear LDS dest),
// frag ds_read_b128 with XOR granule swizzle (conflict-free). 2-phase dbuf:
// stage(next) -> compute(cur) -> __syncthreads (vmcnt drain, m97 pattern).
// Cols [0,1024)=Q (RoPE*QSCALE), [1024,1280)=K (RoPE), [1280,1536)=V
// (transposed + key-permuted store).
__global__ __launch_bounds__(256) void proj_mfma(
    const u16* __restrict__ Xq, const u16* __restrict__ Xk, const u16* __restrict__ Xv,
    const u16* __restrict__ Wt,
    const float* __restrict__ bq, const float* __restrict__ bk, const float* __restrict__ bv,
    const float2* __restrict__ rope,
    u16* __restrict__ Qr, u16* __restrict__ Kr, u16* __restrict__ Vrt)
{
    const int n0 = blockIdx.x * 64, m0 = blockIdx.y * 64;
    const int zone = (n0 < 1024) ? 0 : (n0 < 1280) ? 1 : 2;
    const u16* __restrict__ Az = (zone == 0) ? Xq : (zone == 1) ? Xk : Xv;

    __shared__ __align__(16) u16 As[2][4096];
    __shared__ __align__(16) u16 Bs[2][4096];

    const int t = threadIdx.x;
    const int w = t >> 6, lane = t & 63, lm = lane & 15, quad = lane >> 4;

    f32x4 acc[4] = { {0,0,0,0}, {0,0,0,0}, {0,0,0,0}, {0,0,0,0} };

    const char* Ag = (const char*)(Az + (size_t)(m0 >> 6) * 16 * 4096);
    const char* Bg = (const char*)(Wt + (size_t)(n0 >> 6) * 16 * 4096);

    // wave w stages bytes [w*2048, w*2048+2048) of each 8KB tile (2 issues)
    auto stage = [&](int bufi, int kti) {
        const char* gA = Ag + (size_t)kti * 8192 + w * 2048 + lane * 16;
        const char* gB = Bg + (size_t)kti * 8192 + w * 2048 + lane * 16;
        char* lA = (char*)&As[bufi][0] + w * 2048;
        char* lB = (char*)&Bs[bufi][0] + w * 2048;
        #pragma unroll
        for (int i = 0; i < 2; ++i) {
            __builtin_amdgcn_global_load_lds(
                (const __attribute__((address_space(1))) unsigned int*)(gA + i * 1024),
                (__attribute__((address_space(3))) unsigned int*)(lA + i * 1024), 16, 0, 0);
            __builtin_amdgcn_global_load_lds(
                (const __attribute__((address_space(1))) unsigned int*)(gB + i * 1024),
                (__attribute__((address_space(3))) unsigned int*)(lB + i * 1024), 16, 0, 0);
        }
    };

    stage(0, 0);
    __syncthreads();

    const int rA = 16 * w + lm;
    const int axr = rA & 7;
    for (int kt = 0; kt < 16; ++kt) {
        const int buf = kt & 1;
        if (kt < 15) stage(buf ^ 1, kt + 1);
        const char* Ab = (const char*)&As[buf][0];
        const char* Bb = (const char*)&Bs[buf][0];
        bf16x8 af0 = *reinterpret_cast<const bf16x8*>(Ab + rA * 128 + (((quad    ) ^ axr) << 4));
        bf16x8 af1 = *reinterpret_cast<const bf16x8*>(Ab + rA * 128 + (((4 | quad) ^ axr) << 4));
        #pragma unroll
        for (int nb = 0; nb < 4; ++nb) {
            const int rB = 16 * nb + lm, bxr = rB & 7;
            bf16x8 b0 = *reinterpret_cast<const bf16x8*>(Bb + rB * 128 + (((quad    ) ^ bxr) << 4));
            bf16x8 b1 = *reinterpret_cast<const bf16x8*>(Bb + rB * 128 + (((4 | quad) ^ bxr) << 4));
            acc[nb] = __builtin_amdgcn_mfma_f32_16x16x32_bf16(af0, b0, acc[nb], 0, 0, 0);
            acc[nb] = __builtin_amdgcn_mfma_f32_16x16x32_bf16(af1, b1, acc[nb], 0, 0, 0);
        }
        __syncthreads();
    }

    const float* __restrict__ bias = (zone == 0) ? bq : (zone == 1) ? bk : bv;
    const int nbase = (zone == 0) ? n0 : (zone == 1) ? (n0 - 1024) : (n0 - 1280);
    const int head = nbase >> 6;
    #pragma unroll
    for (int nb = 0; nb < 4; ++nb) {
        const int d = 16 * nb + lm;
        const float bvv = bias[nbase + d];
        float vals[4];
        #pragma unroll
        for (int r = 0; r < 4; ++r) vals[r] = acc[nb][r] + bvv;
        if (zone != 2) {
            const int pi = d >> 1;
            const bool odd = (lm & 1);
            const float sca = (zone == 0) ? QSCALE : 1.0f;
            u16* op = (zone == 0 ? Qr : Kr) + (size_t)head * SEQ * HD;
            #pragma unroll
            for (int r = 0; r < 4; ++r) {
                const int m = m0 + 16 * w + quad * 4 + r;
                const float2 cs2 = rope[(size_t)m * 32 + pi];   // {cos, sin}
                float x  = vals[r];
                float xp = __shfl_xor(x, 1);
                float o  = (odd ? (xp * cs2.y + x * cs2.x)
                                : (x * cs2.x - xp * cs2.y)) * sca;
                op[(size_t)m * HD + d] = f2b(o);
            }
        } else {
            // V transposed [kvh][d][pos], key-PERMUTED within each 64-tile:
            // within = m&63 -> pos = tile*64 + 4*(within&15) + (within>>4)
            u16* vp = Vrt + ((size_t)head * HD + d) * SEQ;
            #pragma unroll
            for (int r = 0; r < 4; ++r) {
                const int m = m0 + 16 * w + quad * 4 + r;
                const int within = m & 63;
                const int pos = (m & ~63) + 4 * (within & 15) + (within >> 4);
                vp[pos] = f2b(vals[r]);
            }
        }
    }
}

// ---------------------------------------------------------------- attention
// 512 blocks x 256 threads (4 waves x 16 q-rows = one 64-row q-tile).
// Block -> (h, qt): h = bid & 15; qt = bid<256 ? bid>>4 : 31-((bid-256)>>4).
// K/V dbuf staged per tile (1 barrier/tile, reg prefetch). P: packed
// col-permuted LDS (c = 4*lm + nb) -> ds_write_b64; V global layout is
// key-permuted to match. Fixed-base exp2 softmax.
__global__ __launch_bounds__(256) void attn_mfma(
    const u16* __restrict__ Qr, const u16* __restrict__ Kr, const u16* __restrict__ Vrt,
    u16* __restrict__ AO)
{
    const int bid = blockIdx.x;
    const int h  = bid & 15;
    const int qt = (bid < 256) ? (bid >> 4) : 31 - ((bid - 256) >> 4);
    const int kvh = h & 3;

    __shared__ u16 Ks[2][64][72];     // [key][d]
    __shared__ u16 Vt[2][64][72];     // [d][c]  (c = permuted key)
    __shared__ u16 Ps[4][16][76];     // per-wave strip; also Q staging

    const int t = threadIdx.x;
    const int w = t >> 6, lane = t & 63, lm = lane & 15, quad = lane >> 4;

    {   // stage this wave's 16 Q rows into its Ps strip (wave-private)
        const int row = lane >> 2, c = (lane & 3) * 16;
        const u16* qp = Qr + ((size_t)h * SEQ + qt * 64 + w * 16 + row) * HD + c;
        *reinterpret_cast<bf16x8*>(&Ps[w][row][c])     = *reinterpret_cast<const bf16x8*>(qp);
        *reinterpret_cast<bf16x8*>(&Ps[w][row][c + 8]) = *reinterpret_cast<const bf16x8*>(qp + 8);
    }
    const bf16x8 aq0 = *reinterpret_cast<const bf16x8*>(&Ps[w][lm][quad * 8]);
    const bf16x8 aq1 = *reinterpret_cast<const bf16x8*>(&Ps[w][lm][32 + quad * 8]);

    f32x4 O[4] = { {0,0,0,0}, {0,0,0,0}, {0,0,0,0}, {0,0,0,0} };   // C[q=quad*4+r][d=16db+lm]
    float lp[4] = { 0.f, 0.f, 0.f, 0.f };

    // staging: 256 threads, 2 b128 each for K and V
    const int srow = t >> 2, sc2 = (t & 3) * 16;
    const u16* kb_ = Kr  + ((size_t)kvh * SEQ + srow) * HD + sc2;   // + kt*64*HD
    const u16* vb_ = Vrt + ((size_t)kvh * HD + srow) * SEQ + sc2;   // + kt*64
    bf16x8 kR0 = *reinterpret_cast<const bf16x8*>(kb_);
    bf16x8 kR1 = *reinterpret_cast<const bf16x8*>(kb_ + 8);
    bf16x8 vR0 = *reinterpret_cast<const bf16x8*>(vb_);
    bf16x8 vR1 = *reinterpret_cast<const bf16x8*>(vb_ + 8);

    for (int kt = 0; kt <= qt; ++kt) {
        const int buf = kt & 1;
        *reinterpret_cast<bf16x8*>(&Ks[buf][srow][sc2])     = kR0;
        *reinterpret_cast<bf16x8*>(&Ks[buf][srow][sc2 + 8]) = kR1;
        *reinterpret_cast<bf16x8*>(&Vt[buf][srow][sc2])     = vR0;
        *reinterpret_cast<bf16x8*>(&Vt[buf][srow][sc2 + 8]) = vR1;
        if (kt < qt) {
            kR0 = *reinterpret_cast<const bf16x8*>(kb_ + (size_t)(kt + 1) * 64 * HD);
            kR1 = *reinterpret_cast<const bf16x8*>(kb_ + (size_t)(kt + 1) * 64 * HD + 8);
            vR0 = *reinterpret_cast<const bf16x8*>(vb_ + (size_t)(kt + 1) * 64);
            vR1 = *reinterpret_cast<const bf16x8*>(vb_ + (size_t)(kt + 1) * 64 + 8);
        }
        __syncthreads();

        f32x4 s[4];
        #pragma unroll
        for (int nb = 0; nb < 4; ++nb) {
            bf16x8 b0 = *reinterpret_cast<const bf16x8*>(&Ks[buf][16 * nb + lm][quad * 8]);
            bf16x8 b1 = *reinterpret_cast<const bf16x8*>(&Ks[buf][16 * nb + lm][32 + quad * 8]);
            f32x4 zz = { 0.f, 0.f, 0.f, 0.f };
            zz = __builtin_amdgcn_mfma_f32_16x16x32_bf16(aq0, b0, zz, 0, 0, 0);
            s[nb] = __builtin_amdgcn_mfma_f32_16x16x32_bf16(aq1, b1, zz, 0, 0, 0);
        }

        if (kt == qt) {   // causal mask (col=16nb+lm, row=16w+quad*4+r)
            #pragma unroll
            for (int nb = 0; nb < 4; ++nb)
                #pragma unroll
                for (int r = 0; r < 4; ++r)
                    if (16 * nb + lm > 16 * w + quad * 4 + r) s[nb][r] = -INFINITY;
        }

        // exp2 + packed P write: row quad*4+r, cols c=4*lm..4*lm+3 (nb)
        #pragma unroll
        for (int r = 0; r < 4; ++r) {
            u16 pk[4];
            #pragma unroll
            for (int nb = 0; nb < 4; ++nb) {
                float e = __builtin_amdgcn_exp2f(fminf(s[nb][r], 126.f));
                lp[r] += e;
                pk[nb] = f2b_fast(e);
            }
            *reinterpret_cast<uint2*>(&Ps[w][quad * 4 + r][4 * lm]) =
                *reinterpret_cast<uint2*>(pk);
        }

        const bf16x8 ap0 = *reinterpret_cast<const bf16x8*>(&Ps[w][lm][quad * 8]);
        const bf16x8 ap1 = *reinterpret_cast<const bf16x8*>(&Ps[w][lm][32 + quad * 8]);
        #pragma unroll
        for (int db = 0; db < 4; ++db) {
            bf16x8 v0 = *reinterpret_cast<const bf16x8*>(&Vt[buf][16 * db + lm][quad * 8]);
            bf16x8 v1 = *reinterpret_cast<const bf16x8*>(&Vt[buf][16 * db + lm][32 + quad * 8]);
            O[db] = __builtin_amdgcn_mfma_f32_16x16x32_bf16(ap0, v0, O[db], 0, 0, 0);
            O[db] = __builtin_amdgcn_mfma_f32_16x16x32_bf16(ap1, v1, O[db], 0, 0, 0);
        }
    }

    #pragma unroll
    for (int r = 0; r < 4; ++r) {
        #pragma unroll
        for (int off = 1; off < 16; off <<= 1)
            lp[r] += __shfl_xor(lp[r], off);
        const float inv = 1.0f / lp[r];
        const size_t row = (size_t)(qt * 64 + 16 * w + quad * 4 + r) * DM + (size_t)h * HD;
        #pragma unroll
        for (int db = 0; db < 4; ++db)
            AO[row + 16 * db + lm] = f2b(O[db][r] * inv);
    }
}

// ---------------------------------------------------------------- output proj
// grid (16, 32): AO bf16 @ Wo^T bf16 + bo -> fp32 out. BK=64, dbuf + prefetch.
__global__ __launch_bounds__(256) void oproj_mfma(
    const u16* __restrict__ AO, const u16* __restrict__ wot,
    const float* __restrict__ bo, float* __restrict__ out)
{
    __shared__ short As[2][64][72];
    __shared__ short Bs[2][64][72];
    const int t = threadIdx.x;
    const int w = t >> 6, lane = t & 63, lm = lane & 15, quad = lane >> 4;
    const int m0 = blockIdx.y * 64, n0 = blockIdx.x * 64;
    const int sr = t >> 2, sc = (t & 3) * 16;

    f32x4 acc[4] = { {0,0,0,0}, {0,0,0,0}, {0,0,0,0}, {0,0,0,0} };

    const u16* ap_ = AO  + (size_t)(m0 + sr) * DM + sc;
    const u16* bp_ = wot + (size_t)(n0 + sr) * DM + sc;
    bf16x8 aR0 = *reinterpret_cast<const bf16x8*>(ap_);
    bf16x8 aR1 = *reinterpret_cast<const bf16x8*>(ap_ + 8);
    bf16x8 bR0 = *reinterpret_cast<const bf16x8*>(bp_);
    bf16x8 bR1 = *reinterpret_cast<const bf16x8*>(bp_ + 8);

    for (int k0 = 0; k0 < DM; k0 += 64) {
        const int buf = (k0 >> 6) & 1;
        *reinterpret_cast<bf16x8*>(&As[buf][sr][sc])     = aR0;
        *reinterpret_cast<bf16x8*>(&As[buf][sr][sc + 8]) = aR1;
        *reinterpret_cast<bf16x8*>(&Bs[buf][sr][sc])     = bR0;
        *reinterpret_cast<bf16x8*>(&Bs[buf][sr][sc + 8]) = bR1;
        if (k0 + 64 < DM) {
            aR0 = *reinterpret_cast<const bf16x8*>(ap_ + k0 + 64);
            aR1 = *reinterpret_cast<const bf16x8*>(ap_ + k0 + 72);
            bR0 = *reinterpret_cast<const bf16x8*>(bp_ + k0 + 64);
            bR1 = *reinterpret_cast<const bf16x8*>(bp_ + k0 + 72);
        }
        __syncthreads();
        bf16x8 af0 = *reinterpret_cast<const bf16x8*>(&As[buf][16 * w + lm][quad * 8]);
        bf16x8 af1 = *reinterpret_cast<const bf16x8*>(&As[buf][16 * w + lm][32 + quad * 8]);
        #pragma unroll
        for (int nb = 0; nb < 4; ++nb) {
            bf16x8 b0 = *reinterpret_cast<const bf16x8*>(&Bs[buf][16 * nb + lm][quad * 8]);
            bf16x8 b1 = *reinterpret_cast<const bf16x8*>(&Bs[buf][16 * nb + lm][32 + quad * 8]);
            acc[nb] = __builtin_amdgcn_mfma_f32_16x16x32_bf16(af0, b0, acc[nb], 0, 0, 0);
            acc[nb] = __builtin_amdgcn_mfma_f32_16x16x32_bf16(af1, b1, acc[nb], 0, 0, 0);
        }
        __syncthreads();
    }

    #pragma unroll
    for (int nb = 0; nb < 4; ++nb) {
        const int dl = 16 * nb + lm;
        const float bv = bo[n0 + dl];
        #pragma unroll
        for (int r = 0; r < 4; ++r) {
            const int m = m0 + 16 * w + quad * 4 + r;
            out[(size_t)m * DM + n0 + dl] = acc[nb][r] + bv;
        }
    }
}

// ---------------------------------------------------------------- launcher
extern "C" void kernel_launch(void* const* d_in, const int* in_sizes, int n_in,
                              void* d_out, int out_size, void* d_ws, size_t ws_size,
                              hipStream_t stream)
{
    const float* q  = (const float*)d_in[0];
    const float* k  = (const float*)d_in[1];
    const float* v  = (const float*)d_in[2];
    // d_in[3] = mask (int32) — causal tril, handled analytically
    const float* Wq = (const float*)d_in[4];
    const float* bq = (const float*)d_in[5];
    const float* Wk = (const float*)d_in[6];
    const float* bk = (const float*)d_in[7];
    const float* Wv = (const float*)d_in[8];
    const float* bv = (const float*)d_in[9];
    const float* Wo = (const float*)d_in[10];
    const float* bo = (const float*)d_in[11];
    float* out = (float*)d_out;

    u16* Xq  = (u16*)d_ws;                          // [32][16] tiles of 64x64 (swz)
    u16* Xk  = Xq  + (size_t)SEQ * DM;
    u16* Xv  = Xk  + (size_t)SEQ * DM;
    u16* Wt  = Xv  + (size_t)SEQ * DM;              // [24][16] tiles of 64x64 (swz)
    u16* wot = Wt  + (size_t)1536 * 1024;           // [1024][1024] row-major
    u16* Qr  = wot + (size_t)1024 * 1024;           // [16][2048][64]
    u16* Kr  = Qr  + (size_t)16 * SEQ * HD;         // [4][2048][64]
    u16* Vrt = Kr  + (size_t)4 * SEQ * HD;          // [4][64][2048] key-permuted
    u16* AO  = Vrt + (size_t)4 * SEQ * HD;          // [2048][1024]
    float2* rope = (float2*)(AO + (size_t)SEQ * DM); // [2048][32] {cos,sin} f32

    hipLaunchKernelGGL(prep_kernel, dim3(1416), dim3(256), 0, stream,
                       q, k, v, Wq, Wk, Wv, Wo, Xq, Xk, Xv, Wt, wot, rope);
    hipLaunchKernelGGL(proj_mfma, dim3(24, 32), dim3(256), 0, stream,
                       Xq, Xk, Xv, Wt, bq, bk, bv, rope, Qr, Kr, Vrt);
    hipLaunchKernelGGL(attn_mfma, dim3(512), dim3(256), 0, stream,
                       Qr, Kr, Vrt, AO);
    hipLaunchKernelGGL(oproj_mfma, dim3(16, 32), dim3(256), 0, stream,
                       AO, wot, bo, out);
}